// Round 8
// baseline (339.313 us; speedup 1.0000x reference)
//
#include <hip/hip_runtime.h>
#include <hip/hip_bf16.h>

typedef __attribute__((ext_vector_type(8))) short bf16x8;
typedef __attribute__((ext_vector_type(8))) unsigned short ushort8;
typedef __attribute__((ext_vector_type(4))) float f32x4;
typedef unsigned int u32;

#define D_DIM 512
#define C_DIM 1024
#define B_DIM 65536

__device__ __forceinline__ unsigned short f2bf(float x) {
  u32 u = __float_as_uint(x);
  u32 r = (u + 0x7fffu + ((u >> 16) & 1u)) >> 16;
  return (unsigned short)r;
}

__device__ __forceinline__ void async16(const void* g, void* l) {
  __builtin_amdgcn_global_load_lds(
      (const __attribute__((address_space(1))) u32*)g,
      (__attribute__((address_space(3))) u32*)l, 16, 0, 0);
}

// sharp(x) = sigmoid(10x-5) + sigmoid(-10x-5)
//          = (E t^2 + 2t + 1) / (E t^2 + (1+E) t + 1),  t = e^(10x-5), E = e^10.
// 1 exp + 1 rcp + 4 fma.  |x|<=1.01 -> t<=161, E t^2 <= 5.7e8 (f32-safe).
__device__ __forceinline__ float sharpf(float x) {
  float t = __expf(10.f * x - 5.f);
  float u = 22026.4658f * t * t;
  float num = u + 2.f * t + 1.f;
  float den = u + 22027.4658f * t + 1.f;
  return num * __builtin_amdgcn_rcpf(den);
}

// Normalize rows of length 512 (l2, +1e-12 eps) and cast to bf16.
__global__ __launch_bounds__(256) void rownorm_kernel(
    const float* __restrict__ src, unsigned short* __restrict__ dst) {
  int row = blockIdx.x * 4 + (threadIdx.x >> 6);
  int lane = threadIdx.x & 63;
  const float* s = src + (size_t)row * D_DIM + lane * 8;
  float4 v0 = *(const float4*)s;
  float4 v1 = *(const float4*)(s + 4);
  float ss = v0.x * v0.x + v0.y * v0.y + v0.z * v0.z + v0.w * v0.w +
             v1.x * v1.x + v1.y * v1.y + v1.z * v1.z + v1.w * v1.w;
#pragma unroll
  for (int m = 32; m >= 1; m >>= 1) ss += __shfl_xor(ss, m);
  float rinv = rsqrtf(ss + 1e-12f);
  float tv[8] = {v0.x, v0.y, v0.z, v0.w, v1.x, v1.y, v1.z, v1.w};
  ushort8 o;
#pragma unroll
  for (int i = 0; i < 8; ++i) o[i] = f2bf(tv[i] * rinv);
  *(ushort8*)(dst + (size_t)row * D_DIM + lane * 8) = o;
}

// vbT[n][k] = bf16(val[k][n])  (transpose+cast, 32x32 LDS tiles)
__global__ __launch_bounds__(256) void valT_kernel(
    const float* __restrict__ val, unsigned short* __restrict__ vbT) {
  __shared__ float tile[32][33];
  int bx = blockIdx.x & 31;  // n tile
  int by = blockIdx.x >> 5;  // k tile
  int t = threadIdx.x;
  int r = t >> 5, c = t & 31;
#pragma unroll
  for (int i = 0; i < 4; ++i)
    tile[r + i * 8][c] = val[(size_t)(by * 32 + r + i * 8) * C_DIM + bx * 32 + c];
  __syncthreads();
#pragma unroll
  for (int i = 0; i < 4; ++i)
    vbT[(size_t)(bx * 32 + r + i * 8) * C_DIM + by * 32 + c] = f2bf(tile[c][r + i * 8]);
}

// rsum[i] = sum of the 4 per-n-block partials
__global__ __launch_bounds__(256) void rsum_reduce_kernel(
    const float* __restrict__ part, float* __restrict__ rsum) {
  int i = blockIdx.x * 256 + threadIdx.x;
  rsum[i] = (part[i] + part[i + B_DIM]) +
            (part[i + 2 * B_DIM] + part[i + 3 * B_DIM]);
}

// 256x256 GEMM, BK=64, 8 waves (2Mx4N), per-wave 128x64, bf16 MFMA 16x16x32.
// Full-tile-ahead double buffer: at head of tile T do [vmcnt(0); s_barrier;
// stage(T+1 -> buf (T+1)&1)]; then the WHOLE tile body (24 ds_reads + 64
// MFMA) runs barrier-free — stages never touch the buffer being read.
// Race ledger: stage(T+1) writes buf d^1; readers of d^1 are tile T-1's
// phases (each wave's ds_reads retire before it reaches BAR(T); BAR(T) orders
// cross-wave) and tile T+1's phases (after BAR(T+1), preceded by vmcnt(0)
// which retires these loads). One barrier + one vmcnt(0) per K-tile.
// SHARP epilogue: sharp -> conflict-free swizzled LDS scatter (phys col ^=
// ((rl>>2)&3)<<4) -> coalesced 16B w store -> LDS wc-reduce of row sums ->
// plain store to rsum_part[n][row].  !SHARP: scale by rcp(rsum[row]), f32.
template <int K, bool SHARP>
__global__ __launch_bounds__(512, 2) void gemm256_kernel(
    const unsigned short* __restrict__ A, const unsigned short* __restrict__ Bm,
    unsigned short* __restrict__ wout, float* __restrict__ rsum,
    float* __restrict__ fout) {
  __shared__ unsigned short smem[65536];  // 128 KB
  const int NKT = K / 64;
  const int bid = blockIdx.x;
  // XCD-chunked bijective swizzle: nwg=1024, 8 XCDs, 128 per chunk.
  const int wg = (bid & 7) * 128 + (bid >> 3);
  const int m0 = (wg >> 2) * 256;
  const int n0 = (wg & 3) * 256;
  const int t = threadIdx.x;
  const int lane = t & 63;
  const int wv = t >> 6;
  const int wr = wv >> 2;  // 0..1
  const int wc = wv & 3;   // 0..3
  const int lo = lane & 15, hi = lane >> 4;
  const int swu = (lo & 7) << 3;  // read-side XOR swizzle (u16 units)

  const int s_ridx = t >> 3;    // 0..63
  const int s_c = (t & 7) * 8;  // phys col, u16
  // stage ALL of K-tile T into buf T&1 (8 gload_lds / thread)
  auto stage = [&](int T) {
    const int d = (T & 1) * 32768;
#pragma unroll
    for (int k = 0; k < 4; ++k) {
      int r = (s_ridx < 32) ? (k * 32 + s_ridx) : (96 + k * 32 + s_ridx);
      int cl = s_c ^ ((r & 7) << 3);  // inverse-swizzled logical col
      size_t go = (size_t)T * 64 + cl;
      async16(A + (size_t)(m0 + r) * K + go, &smem[d + r * 64 + s_c]);
      async16(Bm + (size_t)(n0 + r) * K + go, &smem[d + 16384 + r * 64 + s_c]);
    }
  };

  f32x4 acc[8][4];
#pragma unroll
  for (int i = 0; i < 8; ++i)
#pragma unroll
    for (int j = 0; j < 4; ++j) acc[i][j] = (f32x4){0.f, 0.f, 0.f, 0.f};

  stage(0);  // prologue

#pragma unroll 1
  for (int T = 0; T < NKT; ++T) {
    asm volatile("s_waitcnt vmcnt(0)" ::: "memory");
    __builtin_amdgcn_s_barrier();
    if (T + 1 < NKT) stage(T + 1);
    const int d = (T & 1) * 32768;
    bf16x8 bfr[4][2];
    {  // phase 0: af(mf0,1) + all B; MFMA quadrant 0
      bf16x8 af[2][2];
#pragma unroll
      for (int mi = 0; mi < 2; ++mi)
#pragma unroll
        for (int ks = 0; ks < 2; ++ks) {
          int r = wr * 128 + mi * 16 + lo;
          af[mi][ks] = *(const bf16x8*)&smem[d + r * 64 + ((ks * 32 + hi * 8) ^ swu)];
        }
#pragma unroll
      for (int nf = 0; nf < 4; ++nf)
#pragma unroll
        for (int ks = 0; ks < 2; ++ks) {
          int r = wc * 64 + nf * 16 + lo;
          bfr[nf][ks] =
              *(const bf16x8*)&smem[d + 16384 + r * 64 + ((ks * 32 + hi * 8) ^ swu)];
        }
      __builtin_amdgcn_s_setprio(1);
#pragma unroll
      for (int mi = 0; mi < 2; ++mi)
#pragma unroll
        for (int nf = 0; nf < 4; ++nf)
#pragma unroll
          for (int ks = 0; ks < 2; ++ks)
            acc[mi][nf] = __builtin_amdgcn_mfma_f32_16x16x32_bf16(
                af[mi][ks], bfr[nf][ks], acc[mi][nf], 0, 0, 0);
      __builtin_amdgcn_s_setprio(0);
    }
#pragma unroll
    for (int p = 1; p < 4; ++p) {  // phases 1..3 (no barriers needed)
      bf16x8 af[2][2];
#pragma unroll
      for (int mi = 0; mi < 2; ++mi)
#pragma unroll
        for (int ks = 0; ks < 2; ++ks) {
          int r = wr * 128 + (p * 2 + mi) * 16 + lo;
          af[mi][ks] = *(const bf16x8*)&smem[d + r * 64 + ((ks * 32 + hi * 8) ^ swu)];
        }
      __builtin_amdgcn_s_setprio(1);
#pragma unroll
      for (int mi = 0; mi < 2; ++mi)
#pragma unroll
        for (int nf = 0; nf < 4; ++nf)
#pragma unroll
          for (int ks = 0; ks < 2; ++ks)
            acc[p * 2 + mi][nf] = __builtin_amdgcn_mfma_f32_16x16x32_bf16(
                af[mi][ks], bfr[nf][ks], acc[p * 2 + mi][nf], 0, 0, 0);
      __builtin_amdgcn_s_setprio(0);
    }
  }
  __syncthreads();  // all reads done; no loads outstanding (last head vmcnt 0)

  if (SHARP) {
    float rs[8][4];
#pragma unroll
    for (int i = 0; i < 8; ++i)
#pragma unroll
      for (int j = 0; j < 4; ++j) rs[i][j] = 0.f;
    unsigned short* ep = smem;  // 256x256 u16 = 128 KB
#pragma unroll
    for (int mf = 0; mf < 8; ++mf)
#pragma unroll
      for (int nf = 0; nf < 4; ++nf)
#pragma unroll
        for (int j = 0; j < 4; ++j) {
          float s = sharpf(acc[mf][nf][j]);
          rs[mf][j] += s;
          int rl = wr * 128 + mf * 16 + (hi << 2) + j;
          int cl = (wc * 64 + nf * 16 + lo) ^ (((rl >> 2) & 3) << 4);
          ep[rl * 256 + cl] = f2bf(s);
        }
    // reduce rs over the 16 lo-lanes (butterfly; all lanes end with the sum)
#pragma unroll
    for (int mf = 0; mf < 8; ++mf)
#pragma unroll
      for (int j = 0; j < 4; ++j) {
        float v = rs[mf][j];
        v += __shfl_xor(v, 1);
        v += __shfl_xor(v, 2);
        v += __shfl_xor(v, 4);
        v += __shfl_xor(v, 8);
        rs[mf][j] = v;
      }
    __syncthreads();
    // coalesced 16B/lane store of the 256x256 tile (un-swizzling on read)
#pragma unroll
    for (int pass = 0; pass < 16; ++pass) {
      int idx = pass * 4096 + t * 8;
      int row = idx >> 8, col = idx & 255;
      int phys = row * 256 + (col ^ (((row >> 2) & 3) << 4));
      *(ushort8*)&wout[(size_t)(m0 + row) * C_DIM + n0 + col] =
          *(const ushort8*)&ep[phys];
    }
    __syncthreads();
    // wc-reduction of row sums via 4 KB of LDS, then plain global store
    float* rbuf = (float*)smem;  // [4][256]
    if (lo == 0) {
#pragma unroll
      for (int mf = 0; mf < 8; ++mf)
#pragma unroll
        for (int j = 0; j < 4; ++j)
          rbuf[wc * 256 + wr * 128 + mf * 16 + (hi << 2) + j] = rs[mf][j];
    }
    __syncthreads();
    if (t < 256) {
      float v = (rbuf[t] + rbuf[256 + t]) + (rbuf[512 + t] + rbuf[768 + t]);
      rsum[(size_t)(wg & 3) * B_DIM + m0 + t] = v;  // rsum = rsum_part here
    }
  } else {
    float rinv[8][4];
#pragma unroll
    for (int mf = 0; mf < 8; ++mf) {
      float4 r4 = *(const float4*)&rsum[m0 + wr * 128 + mf * 16 + (hi << 2)];
      rinv[mf][0] = __builtin_amdgcn_rcpf(r4.x);
      rinv[mf][1] = __builtin_amdgcn_rcpf(r4.y);
      rinv[mf][2] = __builtin_amdgcn_rcpf(r4.z);
      rinv[mf][3] = __builtin_amdgcn_rcpf(r4.w);
    }
#pragma unroll
    for (int mf = 0; mf < 8; ++mf)
#pragma unroll
      for (int nf = 0; nf < 4; ++nf)
#pragma unroll
        for (int j = 0; j < 4; ++j)
          fout[(size_t)(m0 + wr * 128 + mf * 16 + (hi << 2) + j) * C_DIM +
               n0 + wc * 64 + nf * 16 + lo] = acc[mf][nf][j] * rinv[mf][j];
  }
}

extern "C" void kernel_launch(void* const* d_in, const int* in_sizes, int n_in,
                              void* d_out, int out_size, void* d_ws, size_t ws_size,
                              hipStream_t stream) {
  const float* query = (const float*)d_in[0];
  const float* key = (const float*)d_in[1];
  const float* val = (const float*)d_in[2];
  float* out = (float*)d_out;
  const int B = in_sizes[0] / D_DIM;  // 65536

  char* ws = (char*)d_ws;
  unsigned short* kb = (unsigned short*)(ws);                         // 1 MB
  unsigned short* vbT = (unsigned short*)(ws + (1ull << 20));         // 2 MB
  float* rsum_part = (float*)(ws + 3ull * (1ull << 20));              // 1 MB
  unsigned short* qb = (unsigned short*)(ws + 4ull * (1ull << 20));   // 64 MB
  float* rsum = (float*)qb;  // reuses qb region (dead after GEMM1)
  unsigned short* wbf = (unsigned short*)(ws + 68ull * (1ull << 20)); // 128 MB

  rownorm_kernel<<<dim3(B / 4), dim3(256), 0, stream>>>(query, qb);
  rownorm_kernel<<<dim3(C_DIM / 4), dim3(256), 0, stream>>>(key, kb);
  valT_kernel<<<dim3(1024), dim3(256), 0, stream>>>(val, vbT);

  dim3 grid((B / 256) * (C_DIM / 256));  // 1024 blocks
  gemm256_kernel<D_DIM, true><<<grid, dim3(512), 0, stream>>>(qb, kb, wbf, rsum_part, nullptr);
  rsum_reduce_kernel<<<dim3(B / 256), dim3(256), 0, stream>>>(rsum_part, rsum);
  gemm256_kernel<C_DIM, false><<<grid, dim3(512), 0, stream>>>(wbf, vbT, nullptr, rsum, out);
}